// Round 9
// baseline (696.584 us; speedup 1.0000x reference)
//
#include <hip/hip_runtime.h>

typedef unsigned short u16;
typedef __bf16 bf16_t;
typedef bf16_t bf16x8 __attribute__((ext_vector_type(8)));
typedef float f32x4 __attribute__((ext_vector_type(4)));
typedef u16 u16x8 __attribute__((ext_vector_type(8)));

#define AS1 __attribute__((address_space(1)))
#define AS3 __attribute__((address_space(3)))

__device__ __forceinline__ u16 f2bf(float f) {
    union { float f; unsigned u; } v; v.f = f;
    unsigned r = v.u + 0x7FFFu + ((v.u >> 16) & 1u);
    return (u16)(r >> 16);
}
__device__ __forceinline__ float bf2f(u16 s) {
    union { unsigned u; float f; } v; v.u = ((unsigned)s) << 16;
    return v.f;
}

__device__ __forceinline__ void gload_lds16(const u16* g, u16* l) {
    __builtin_amdgcn_global_load_lds((AS1 const void*)g, (AS3 void*)l, 16, 0, 0);
}

// ---------------- big GEMM: C[M,N] = A[M,K] * B[N,K]^T, bf16 in, 128x128 tile ----
template <bool OUT_BF16, bool GUARD>
__global__ __launch_bounds__(256) void gemm_bt(
    const u16* __restrict__ A, const u16* __restrict__ B, void* __restrict__ Cv,
    int K, int ldc, int Mreal, int Nreal)
{
    __shared__ u16 As[128 * 64];
    __shared__ u16 Bs[128 * 64];
    const int t = threadIdx.x;
    const int w = t >> 6, l = t & 63;

    const int nwg = gridDim.x * gridDim.y;
    const int lin = blockIdx.y * gridDim.x + blockIdx.x;
    const int xcd = lin & 7, loc = lin >> 3;
    const int q = nwg >> 3, r = nwg & 7;
    const int swz = (xcd < r ? xcd * (q + 1) : r * (q + 1) + (xcd - r) * q) + loc;
    const int bx = swz % gridDim.x, by = swz / gridDim.x;

    const int m0 = by * 128, n0 = bx * 128;
    const int wm = (w >> 1) * 64, wn = (w & 1) * 64;

    const int srow = w << 5;
    const int lrow = l >> 3, lc = l & 7;

    f32x4 acc[4][4] = {};

    for (int kt = 0; kt < K; kt += 64) {
#pragma unroll
        for (int i = 0; i < 4; ++i) {
            int row = srow + i * 8 + lrow;
            int gc = ((lc ^ (row & 7)) << 3);
            const u16* ga = A + (size_t)(m0 + row) * K + kt + gc;
            const u16* gb = B + (size_t)(n0 + row) * K + kt + gc;
            u16* la = &As[(srow + i * 8) * 64];
            u16* lb = &Bs[(srow + i * 8) * 64];
            gload_lds16(ga, la);
            gload_lds16(gb, lb);
        }
        asm volatile("s_waitcnt vmcnt(0)");
        __syncthreads();

#pragma unroll
        for (int kk = 0; kk < 2; ++kk) {
            bf16x8 af[4], bfr[4];
            int kc = kk * 4 + (l >> 4);
#pragma unroll
            for (int mi = 0; mi < 4; ++mi) {
                int row = wm + mi * 16 + (l & 15);
                af[mi] = *(const bf16x8*)&As[row * 64 + ((kc ^ (row & 7)) << 3)];
            }
#pragma unroll
            for (int ni = 0; ni < 4; ++ni) {
                int col = wn + ni * 16 + (l & 15);
                bfr[ni] = *(const bf16x8*)&Bs[col * 64 + ((kc ^ (col & 7)) << 3)];
            }
#pragma unroll
            for (int mi = 0; mi < 4; ++mi)
#pragma unroll
                for (int ni = 0; ni < 4; ++ni)
                    acc[mi][ni] = __builtin_amdgcn_mfma_f32_16x16x32_bf16(
                        af[mi], bfr[ni], acc[mi][ni], 0, 0, 0);
        }
        __syncthreads();
    }

#pragma unroll
    for (int mi = 0; mi < 4; ++mi) {
#pragma unroll
        for (int qq = 0; qq < 4; ++qq) {
            int row = m0 + wm + mi * 16 + (l >> 4) * 4 + qq;
            if (GUARD && row >= Mreal) continue;
#pragma unroll
            for (int ni = 0; ni < 4; ++ni) {
                int col = n0 + wn + ni * 16 + (l & 15);
                if (GUARD && col >= Nreal) continue;
                float v = acc[mi][ni][qq];
                if (OUT_BF16) ((u16*)Cv)[(size_t)row * ldc + col] = f2bf(v);
                else          ((float*)Cv)[(size_t)row * ldc + col] = v;
            }
        }
    }
}

// ---------------- fused conv+GEMM1 v3: 2-deep A reg prefetch ----------------
// Issue order per phase: stageB(t+1) THEN loadA(t+2); vmcnt(20) drains exactly
// B(t) (in-order retirement) while A(t+1),B(t+1),A(t+2)=20 ops stay in flight.
// A latency gets ~2 phases of cover. Macros (not lambdas) for static reg indexing.

#define LOADA(KT, PA)                                                         \
    {                                                                         \
        int c_ = (KT) + lc * 8;                                               \
        bool okc_ = c_ < 3000;                                                \
        _Pragma("unroll")                                                     \
        for (int i_ = 0; i_ < 4; ++i_) {                                      \
            bool ok_ = okr[i_] && okc_;                                       \
            const float* p_ = X + (ok_ ? ((size_t)rowg[i_] * 3000 + c_) : 0); \
            float4 v0_ = *(const float4*)p_;                                  \
            float4 v1_ = *(const float4*)(p_ + 4);                            \
            if (!ok_) { v0_ = make_float4(0.f, 0.f, 0.f, 0.f); v1_ = v0_; }   \
            PA[i_][0] = v0_;                                                  \
            PA[i_][1] = v1_;                                                  \
        }                                                                     \
    }

#define STAGEB(KT2, BUF)                                                      \
    {                                                                         \
        _Pragma("unroll")                                                     \
        for (int i_ = 0; i_ < 4; ++i_) {                                      \
            int row_ = srow + i_ * 8 + lrow;                                  \
            int gc_ = ((lc ^ (row_ & 7)) << 3);                               \
            gload_lds16(Bw + (size_t)(n0 + row_) * 3008 + (KT2) + gc_,        \
                        &Bs[BUF][(srow + i_ * 8) * 64]);                      \
        }                                                                     \
    }

#define PHASE(KT, PA)                                                         \
    {                                                                         \
        const int kt_ = (KT);                                                 \
        if (do_s) {                                                           \
            int c_ = kt_ + lc * 8;                                            \
            float4 d0_ = *(const float4*)(vd + c_);                           \
            float4 d1_ = *(const float4*)(vd + c_ + 4);                       \
            float4 s0_ = *(const float4*)(vs + c_);                           \
            float4 s1_ = *(const float4*)(vs + c_ + 4);                       \
            _Pragma("unroll")                                                 \
            for (int i_ = 0; i_ < 4; ++i_) {                                  \
                sdp[i_] += PA[i_][0].x * d0_.x + PA[i_][0].y * d0_.y          \
                         + PA[i_][0].z * d0_.z + PA[i_][0].w * d0_.w          \
                         + PA[i_][1].x * d1_.x + PA[i_][1].y * d1_.y          \
                         + PA[i_][1].z * d1_.z + PA[i_][1].w * d1_.w;         \
                ssp[i_] += PA[i_][0].x * s0_.x + PA[i_][0].y * s0_.y          \
                         + PA[i_][0].z * s0_.z + PA[i_][0].w * s0_.w          \
                         + PA[i_][1].x * s1_.x + PA[i_][1].y * s1_.y          \
                         + PA[i_][1].z * s1_.z + PA[i_][1].w * s1_.w;         \
            }                                                                 \
        }                                                                     \
        _Pragma("unroll")                                                     \
        for (int i_ = 0; i_ < 4; ++i_) {                                      \
            int row_ = srow + i_ * 8 + lrow;                                  \
            bf16x8 o_;                                                        \
            o_[0] = (bf16_t)PA[i_][0].x; o_[1] = (bf16_t)PA[i_][0].y;         \
            o_[2] = (bf16_t)PA[i_][0].z; o_[3] = (bf16_t)PA[i_][0].w;         \
            o_[4] = (bf16_t)PA[i_][1].x; o_[5] = (bf16_t)PA[i_][1].y;         \
            o_[6] = (bf16_t)PA[i_][1].z; o_[7] = (bf16_t)PA[i_][1].w;         \
            *(bf16x8*)&As[row_ * 64 + ((lc ^ (row_ & 7)) << 3)] = o_;         \
        }                                                                     \
        STAGEB((kt_ + 64 < 3008) ? kt_ + 64 : 2944, cur ^ 1);                 \
        LOADA(kt_ + 128, PA);                                                 \
        asm volatile("s_waitcnt vmcnt(20) lgkmcnt(0)" ::: "memory");          \
        __builtin_amdgcn_s_barrier();                                         \
        _Pragma("unroll")                                                     \
        for (int kk_ = 0; kk_ < 2; ++kk_) {                                   \
            bf16x8 af_[4], bf_[4];                                            \
            int kc_ = kk_ * 4 + (l >> 4);                                     \
            _Pragma("unroll")                                                 \
            for (int mi_ = 0; mi_ < 4; ++mi_) {                               \
                int row_ = wm + mi_ * 16 + (l & 15);                          \
                af_[mi_] = *(const bf16x8*)&As[row_ * 64 + ((kc_ ^ (row_ & 7)) << 3)]; \
            }                                                                 \
            _Pragma("unroll")                                                 \
            for (int ni_ = 0; ni_ < 4; ++ni_) {                               \
                int col_ = wn + ni_ * 16 + (l & 15);                          \
                bf_[ni_] = *(const bf16x8*)&Bs[cur][col_ * 64 + ((kc_ ^ (col_ & 7)) << 3)]; \
            }                                                                 \
            _Pragma("unroll")                                                 \
            for (int mi_ = 0; mi_ < 4; ++mi_)                                 \
                _Pragma("unroll")                                             \
                for (int ni_ = 0; ni_ < 4; ++ni_)                             \
                    acc[mi_][ni_] = __builtin_amdgcn_mfma_f32_16x16x32_bf16(  \
                        af_[mi_], bf_[ni_], acc[mi_][ni_], 0, 0, 0);          \
        }                                                                     \
        asm volatile("s_barrier" ::: "memory");                               \
        cur ^= 1;                                                             \
    }

__global__ __launch_bounds__(256) void gemm_xw2(
    const float* __restrict__ X, const u16* __restrict__ Bw, u16* __restrict__ C,
    const float* __restrict__ vd, const float* __restrict__ vs,
    float* __restrict__ sd, float* __restrict__ ss)
{
    __shared__ u16 As[128 * 64];
    __shared__ u16 Bs[2][128 * 64];
    const int t = threadIdx.x;
    const int w = t >> 6, l = t & 63;

    const int nwg = gridDim.x * gridDim.y;   // (4,235)
    const int lin = blockIdx.y * gridDim.x + blockIdx.x;
    const int xcd = lin & 7, loc = lin >> 3;
    const int q = nwg >> 3, r = nwg & 7;
    const int swz = (xcd < r ? xcd * (q + 1) : r * (q + 1) + (xcd - r) * q) + loc;
    const int bx = swz % gridDim.x, by = swz / gridDim.x;

    const int m0 = by * 128, n0 = bx * 128;
    const int wm = (w >> 1) * 64, wn = (w & 1) * 64;
    const int srow = w << 5;
    const int lrow = l >> 3, lc = l & 7;

    f32x4 acc[4][4] = {};
    float sdp[4] = {}, ssp[4] = {};
    const bool do_s = (bx == 0);

    int rowg[4];
    bool okr[4];
#pragma unroll
    for (int i = 0; i < 4; ++i) {
        rowg[i] = m0 + srow + i * 8 + lrow;
        okr[i] = rowg[i] < 30000;
    }

    float4 paA[4][2], paB[4][2];

    LOADA(0, paA);       // 8 vm
    STAGEB(0, 0);        // 4 vm
    LOADA(64, paB);      // 8 vm
    int cur = 0;

    for (int kt = 0; kt < 2944; kt += 128) {
        PHASE(kt, paA);
        PHASE(kt + 64, paB);
    }
    PHASE(2944, paA);    // 47th phase

    if (do_s) {
#pragma unroll
        for (int i = 0; i < 4; ++i) {
            float a = sdp[i], b = ssp[i];
            a += __shfl_xor(a, 1); a += __shfl_xor(a, 2); a += __shfl_xor(a, 4);
            b += __shfl_xor(b, 1); b += __shfl_xor(b, 2); b += __shfl_xor(b, 4);
            if (lc == 0 && okr[i]) { sd[rowg[i]] = a; ss[rowg[i]] = b; }
        }
    }

#pragma unroll
    for (int mi = 0; mi < 4; ++mi)
#pragma unroll
        for (int qq = 0; qq < 4; ++qq) {
            int row = m0 + wm + mi * 16 + (l >> 4) * 4 + qq;
#pragma unroll
            for (int ni = 0; ni < 4; ++ni) {
                int col = n0 + wn + ni * 16 + (l & 15);
                C[(size_t)row * 512 + col] = f2bf(acc[mi][ni][qq]);
            }
        }
}

// ---------------- merged prep: vd/vs | w1sb | w1st | w2b | deg ----------------
__global__ void k_prep(const float* __restrict__ W1d, const float* __restrict__ a1d,
                       const float* __restrict__ W1s, const float* __restrict__ a1s,
                       const float* __restrict__ W2s, const int* __restrict__ dst,
                       float* __restrict__ vd, float* __restrict__ vs,
                       u16* __restrict__ w1sb, u16* __restrict__ w1st,
                       u16* __restrict__ w2sb, unsigned* __restrict__ deg) {
    int b = blockIdx.x, t = threadIdx.x;
    if (b < 12) {
        int i = b * 256 + t;
        if (i >= 3000) {
            if (i < 3008) { vd[i] = 0.f; vs[i] = 0.f; }   // zero K-pad
            return;
        }
        float ad = 0.f, as = 0.f;
        for (int h = 0; h < 512; ++h) {
            ad += W1d[(size_t)h * 3000 + i] * a1d[h];
            as += W1s[(size_t)h * 3000 + i] * a1s[h];
        }
        vd[i] = ad;
        vs[i] = as;
    } else if (b < 1516) {
        int idx = (b - 12) * 256 + t;          // 512*752
        int n = idx / 752, k = (idx % 752) * 4;
        ushort4 o = make_ushort4(0, 0, 0, 0);
        if (k < 3000) {
            float4 v = *(const float4*)(W1s + (size_t)n * 3000 + k);
            o.x = f2bf(v.x); o.y = f2bf(v.y); o.z = f2bf(v.z); o.w = f2bf(v.w);
        }
        *(ushort4*)(w1sb + (size_t)n * 3008 + k) = o;
    } else if (b < 1900) {
        __shared__ float tile[64][65];
        int fb = b - 1516;
        int i0 = (fb % 48) * 64, h0 = (fb / 48) * 64;
        int il = t & 63, hq = t >> 6;
#pragma unroll
        for (int rr = 0; rr < 16; ++rr) {
            int hl = rr * 4 + hq;
            int i = i0 + il;
            tile[hl][il] = (i < 3000) ? W1s[(size_t)(h0 + hl) * 3000 + i] : 0.f;
        }
        __syncthreads();
#pragma unroll
        for (int rr = 0; rr < 16; ++rr) {
            int il2 = rr * 4 + hq;
            w1st[(size_t)(i0 + il2) * 512 + h0 + il] = f2bf(tile[il][il2]);
        }
    } else if (b < 2156) {
        int idx = (b - 1900) * 256 + t;        // 128*512
        int n = idx >> 9, k = idx & 511;
        w2sb[idx] = (n < 30) ? f2bf(W2s[(size_t)n * 512 + k]) : (u16)0;
    } else {
        int j = (b - 2156) * 256 + t;
        if (j < 180000) atomicAdd(&deg[dst[j]], 1u);
    }
}

// ---------------- scan stage 1: per-block sums ----------------
__global__ void k_scan1(const unsigned* __restrict__ deg, unsigned* __restrict__ bsum, int n) {
    __shared__ unsigned ws[4];
    int i = blockIdx.x * 256 + threadIdx.x;
    unsigned v = (i < n) ? deg[i] : 0u;
#pragma unroll
    for (int s = 32; s; s >>= 1) v += __shfl_xor(v, s);
    if ((threadIdx.x & 63) == 0) ws[threadIdx.x >> 6] = v;
    __syncthreads();
    if (threadIdx.x == 0) bsum[blockIdx.x] = ws[0] + ws[1] + ws[2] + ws[3];
}

// ---------------- scan stage 2: per-block offset via masked wave-sum + local scan --
__global__ void k_scanB(const unsigned* __restrict__ deg, const unsigned* __restrict__ bsum,
                        unsigned* __restrict__ off, unsigned* __restrict__ cur,
                        int n, int nb) {
    __shared__ unsigned tmp[256];
    __shared__ unsigned bo;
    int b = blockIdx.x, t = threadIdx.x, i = b * 256 + t;
    if (t < 64) {
        unsigned s0 = (t < nb) ? bsum[t] : 0u;
        unsigned s1 = (t + 64 < nb) ? bsum[t + 64] : 0u;
        unsigned v = ((t < b) ? s0 : 0u) + ((t + 64 < b) ? s1 : 0u);
#pragma unroll
        for (int s = 32; s; s >>= 1) v += __shfl_xor(v, s);
        if (t == 0) bo = v;
        if (b == nb - 1) {
            unsigned tv = s0 + s1;
#pragma unroll
            for (int s = 32; s; s >>= 1) tv += __shfl_xor(tv, s);
            if (t == 0) off[n] = tv;
        }
    }
    __syncthreads();
    unsigned v = (i < n) ? deg[i] : 0u;
    tmp[t] = v;
    __syncthreads();
    for (int s = 1; s < 256; s <<= 1) {
        unsigned a = (t >= s) ? tmp[t - s] : 0u;
        __syncthreads();
        tmp[t] += a;
        __syncthreads();
    }
    if (i < n) {
        unsigned o = bo + tmp[t] - v;
        off[i] = o;
        cur[i] = o;
    }
}

__global__ void k_fill(const int* __restrict__ dst, unsigned* __restrict__ cur,
                       unsigned* __restrict__ csr) {
    int j = blockIdx.x * 256 + threadIdx.x;
    if (j >= 180000) return;
    unsigned pos = atomicAdd(&cur[dst[j]], 1u);
    csr[pos] = (unsigned)j;
}

// ---------------- fused score+softmax: alpha from ss/sd, 8-lane groups ----------
__global__ void k_soft(const int* __restrict__ src, const float* __restrict__ ss,
                       const float* __restrict__ sd, float* __restrict__ alpha,
                       const unsigned* __restrict__ csr, const unsigned* __restrict__ off) {
    int t = threadIdx.x;
    int g = t >> 3, l = t & 7;
    int n = blockIdx.x * 32 + g;
    if (n >= 30000) return;
    unsigned lo = off[n], hi = off[n + 1];
    if (lo == hi) return;
    float sdn = sd[n];
    float m = -1e30f;
    for (unsigned i = lo + l; i < hi; i += 8) {
        float v = ss[src[csr[i]]] + sdn;
        v = v > 0.f ? v : 0.2f * v;
        m = fmaxf(m, v);
    }
    m = fmaxf(m, __shfl_xor(m, 1));
    m = fmaxf(m, __shfl_xor(m, 2));
    m = fmaxf(m, __shfl_xor(m, 4));
    float den = 0.f;
    for (unsigned i = lo + l; i < hi; i += 8) {
        float v = ss[src[csr[i]]] + sdn;
        v = v > 0.f ? v : 0.2f * v;
        den += expf(v - m);
    }
    den += __shfl_xor(den, 1);
    den += __shfl_xor(den, 2);
    den += __shfl_xor(den, 4);
    float inv = 1.f / den;
    for (unsigned i = lo + l; i < hi; i += 8) {
        unsigned j = csr[i];
        float v = ss[src[j]] + sdn;
        v = v > 0.f ? v : 0.2f * v;
        alpha[j] = expf(v - m) * inv;
    }
}

// ---------------- aggregation + ELU: wave per node, 2-edge pipelined gathers ------
__global__ void k_agg(const u16* __restrict__ xin, const float* __restrict__ alpha,
                      const unsigned* __restrict__ csr, const unsigned* __restrict__ off,
                      const int* __restrict__ src, u16* __restrict__ outb, int nvalid) {
    int w = threadIdx.x >> 6, l = threadIdx.x & 63;
    int n = blockIdx.x * 4 + w;
    float acc[8] = {};
    if (n < nvalid) {
        unsigned lo = off[n], hi = off[n + 1];
        unsigned i = lo;
        for (; i + 2 <= hi; i += 2) {
            unsigned j0 = csr[i], j1 = csr[i + 1];
            float a0 = alpha[j0], a1 = alpha[j1];
            int s0 = src[j0], s1 = src[j1];
            u16x8 r0 = *(const u16x8*)&xin[(size_t)s0 * 512 + l * 8];
            u16x8 r1 = *(const u16x8*)&xin[(size_t)s1 * 512 + l * 8];
#pragma unroll
            for (int k = 0; k < 8; ++k) acc[k] += a0 * bf2f(r0[k]) + a1 * bf2f(r1[k]);
        }
        if (i < hi) {
            unsigned j0 = csr[i];
            float a0 = alpha[j0];
            int s0 = src[j0];
            u16x8 r0 = *(const u16x8*)&xin[(size_t)s0 * 512 + l * 8];
#pragma unroll
            for (int k = 0; k < 8; ++k) acc[k] += a0 * bf2f(r0[k]);
        }
    }
    u16x8 o;
#pragma unroll
    for (int k = 0; k < 8; ++k) {
        float a = acc[k] > 0.f ? acc[k] : expf(acc[k]) - 1.f;
        o[k] = f2bf(a);
    }
    *(u16x8*)&outb[(size_t)n * 512 + l * 8] = o;
}

// ---------------- aggG: g[n,:] = sum alpha_e * h2[src_e,:]  (30-wide fp32) -------
__global__ void k_aggG(const float* __restrict__ h2, const float* __restrict__ alpha,
                       const unsigned* __restrict__ csr, const unsigned* __restrict__ off,
                       const int* __restrict__ src, float* __restrict__ g) {
    int t = threadIdx.x, grp = t >> 3, l = t & 7;
    int n = blockIdx.x * 32 + grp;
    if (n >= 30000) return;
    unsigned lo = off[n], hi = off[n + 1];
    float acc[4] = {};
    int c0 = l * 4;
    for (unsigned i = lo; i < hi; ++i) {
        unsigned j = csr[i];
        float a = alpha[j];
        const float* row = h2 + (size_t)src[j] * 30;
#pragma unroll
        for (int k = 0; k < 4; ++k) {
            int c = c0 + k;
            if (c < 30) acc[k] += a * row[c];
        }
    }
#pragma unroll
    for (int k = 0; k < 4; ++k) {
        int c = c0 + k;
        if (c < 30) g[(size_t)n * 30 + c] = acc[k];
    }
}

// ---------------- h3[n,:] = elu(g[n,:] @ W2s)  -> bf16 [30080][512] -------------
__global__ void k_h3(const float* __restrict__ g, const float* __restrict__ W2s,
                     u16* __restrict__ h3b) {
    int t = threadIdx.x;
    size_t n0 = (size_t)blockIdx.x * 8;
    float w0[30], w1[30];
#pragma unroll
    for (int o = 0; o < 30; ++o) {
        w0[o] = W2s[(size_t)o * 512 + t];
        w1[o] = W2s[(size_t)o * 512 + t + 256];
    }
    for (int rr = 0; rr < 8; ++rr) {
        size_t n = n0 + rr;
        float a0 = 0.f, a1 = 0.f;
        if (n < 30000) {
            const float* gr = g + n * 30;
#pragma unroll
            for (int o = 0; o < 30; ++o) {
                float v = gr[o];
                a0 += v * w0[o];
                a1 += v * w1[o];
            }
            a0 = a0 > 0.f ? a0 : expf(a0) - 1.f;
            a1 = a1 > 0.f ? a1 : expf(a1) - 1.f;
        }
        h3b[n * 512 + t] = f2bf(a0);
        h3b[n * 512 + t + 256] = f2bf(a1);
    }
}

extern "C" void kernel_launch(void* const* d_in, const int* in_sizes, int n_in,
                              void* d_out, int out_size, void* d_ws, size_t ws_size,
                              hipStream_t stream) {
    const float* X   = (const float*)d_in[0];
    const int*   ei  = (const int*)d_in[1];
    const float* W1s = (const float*)d_in[2];
    const float* W1d = (const float*)d_in[3];
    const float* a1s = (const float*)d_in[4];
    const float* a1d = (const float*)d_in[5];
    const float* W2s = (const float*)d_in[6];
    const int* src = ei;
    const int* dst = ei + 180000;

    float* out = (float*)d_out;
    float* h2 = out;               // [30000][30]
    float* h4 = out + 900000;      // [30000][3000]

    // scratch inside d_out h4 region (dead before gemm5 overwrites it)
    char* ob = (char*)(out + 900000);
    u16* xs1b = (u16*)ob;                                  // 30080*512
    u16* h1b  = (u16*)(ob + 30801920);                     // 30080*512
    float* g  = (float*)(ob + 30801920 + 30801920);        // 30000*30 fp32

    // ws scratch (must survive gemm5): h3b + W1sT + small vectors
    char* w = (char*)d_ws;
    auto carve = [&](size_t bytes) { char* p = w; w += (bytes + 255) & ~(size_t)255; return p; };
    u16* w1sb  = (u16*)carve((size_t)512 * 3008 * 2);
    u16* w1st  = (u16*)carve((size_t)3072 * 512 * 2);
    u16* w2sb  = (u16*)carve((size_t)128 * 512 * 2);
    u16* h3b   = (u16*)carve((size_t)30080 * 512 * 2);
    float* vd    = (float*)carve(3008 * 4);
    float* vs    = (float*)carve(3008 * 4);
    float* ss    = (float*)carve(30000 * 4);
    float* sd    = (float*)carve(30000 * 4);
    float* alpha = (float*)carve(180000 * 4);
    unsigned* deg = (unsigned*)carve(30000 * 4);
    unsigned* off = (unsigned*)carve(30004 * 4);
    unsigned* cur = (unsigned*)carve(30000 * 4);
    unsigned* csr = (unsigned*)carve(180000 * 4);
    unsigned* bsum = (unsigned*)carve(128 * 4);

    hipMemsetAsync(deg, 0, 30000 * 4, stream);

    // merged prep: vd/vs | w1sb | w1st | w2sb | deg
    k_prep<<<2860, 256, 0, stream>>>(W1d, a1d, W1s, a1s, W2s, dst,
                                     vd, vs, w1sb, w1st, w2sb, deg);

    // fused: xs1 = bf16(X) @ W1s^T  +  sd/ss  (2-deep A prefetch)
    gemm_xw2<<<dim3(4, 235), 256, 0, stream>>>(X, w1sb, xs1b, vd, vs, sd, ss);

    k_scan1<<<118, 256, 0, stream>>>(deg, bsum, 30000);
    k_scanB<<<118, 256, 0, stream>>>(deg, bsum, off, cur, 30000, 118);
    k_fill<<<704, 256, 0, stream>>>(dst, cur, csr);
    k_soft<<<938, 256, 0, stream>>>(src, ss, sd, alpha, csr, off);

    k_agg <<<7520, 256, 0, stream>>>(xs1b, alpha, csr, off, src, h1b, 30000);

    // h2 = h1 @ W2s.T via MFMA
    gemm_bt<false, true><<<dim3(1, 235), 256, 0, stream>>>(h1b, w2sb, h2, 512, 30, 30000, 30);

    // g = agg(alpha, h2);  h3 = elu(g @ W2s)   [agg commutes with linear map]
    k_aggG<<<938, 256, 0, stream>>>(h2, alpha, csr, off, src, g);
    k_h3 <<<3760, 256, 0, stream>>>(g, W2s, h3b);

    gemm_bt<false, true><<<dim3(24, 235), 256, 0, stream>>>(h3b, w1st, h4, 512, 3000, 30000, 3000);
}

// Round 10
// 640.730 us; speedup vs baseline: 1.0872x; 1.0872x over previous
//
#include <hip/hip_runtime.h>

typedef unsigned short u16;
typedef __bf16 bf16_t;
typedef bf16_t bf16x8 __attribute__((ext_vector_type(8)));
typedef float f32x4 __attribute__((ext_vector_type(4)));
typedef u16 u16x8 __attribute__((ext_vector_type(8)));

#define AS1 __attribute__((address_space(1)))
#define AS3 __attribute__((address_space(3)))

__device__ __forceinline__ u16 f2bf(float f) {
    union { float f; unsigned u; } v; v.f = f;
    unsigned r = v.u + 0x7FFFu + ((v.u >> 16) & 1u);
    return (u16)(r >> 16);
}
__device__ __forceinline__ float bf2f(u16 s) {
    union { unsigned u; float f; } v; v.u = ((unsigned)s) << 16;
    return v.f;
}

__device__ __forceinline__ void gload_lds16(const u16* g, u16* l) {
    __builtin_amdgcn_global_load_lds((AS1 const void*)g, (AS3 void*)l, 16, 0, 0);
}

// ---------------- big GEMM: C[M,N] = A[M,K] * B[N,K]^T, bf16 in, 128x128 tile ----
// Flat persistent grid: real blocks grid-stride over vgx*vgy virtual tiles.
template <bool OUT_BF16, bool GUARD>
__global__ __launch_bounds__(256) void gemm_bt(
    const u16* __restrict__ A, const u16* __restrict__ B, void* __restrict__ Cv,
    int K, int ldc, int Mreal, int Nreal, int vgx, int vgy)
{
    __shared__ u16 As[128 * 64];
    __shared__ u16 Bs[128 * 64];
    const int t = threadIdx.x;
    const int w = t >> 6, l = t & 63;
    const int wm = (w >> 1) * 64, wn = (w & 1) * 64;
    const int srow = w << 5;
    const int lrow = l >> 3, lc = l & 7;
    const int nwg = vgx * vgy;
    const int q = nwg >> 3, r = nwg & 7;

    for (int vb = blockIdx.x; vb < nwg; vb += gridDim.x) {
        const int xcd = vb & 7, loc = vb >> 3;
        const int swz = (xcd < r ? xcd * (q + 1) : r * (q + 1) + (xcd - r) * q) + loc;
        const int bx = swz % vgx, by = swz / vgx;
        const int m0 = by * 128, n0 = bx * 128;

        f32x4 acc[4][4] = {};

        for (int kt = 0; kt < K; kt += 64) {
#pragma unroll
            for (int i = 0; i < 4; ++i) {
                int row = srow + i * 8 + lrow;
                int gc = ((lc ^ (row & 7)) << 3);
                const u16* ga = A + (size_t)(m0 + row) * K + kt + gc;
                const u16* gb = B + (size_t)(n0 + row) * K + kt + gc;
                gload_lds16(ga, &As[(srow + i * 8) * 64]);
                gload_lds16(gb, &Bs[(srow + i * 8) * 64]);
            }
            asm volatile("s_waitcnt vmcnt(0)");
            __syncthreads();

#pragma unroll
            for (int kk = 0; kk < 2; ++kk) {
                bf16x8 af[4], bfr[4];
                int kc = kk * 4 + (l >> 4);
#pragma unroll
                for (int mi = 0; mi < 4; ++mi) {
                    int row = wm + mi * 16 + (l & 15);
                    af[mi] = *(const bf16x8*)&As[row * 64 + ((kc ^ (row & 7)) << 3)];
                }
#pragma unroll
                for (int ni = 0; ni < 4; ++ni) {
                    int col = wn + ni * 16 + (l & 15);
                    bfr[ni] = *(const bf16x8*)&Bs[col * 64 + ((kc ^ (col & 7)) << 3)];
                }
#pragma unroll
                for (int mi = 0; mi < 4; ++mi)
#pragma unroll
                    for (int ni = 0; ni < 4; ++ni)
                        acc[mi][ni] = __builtin_amdgcn_mfma_f32_16x16x32_bf16(
                            af[mi], bfr[ni], acc[mi][ni], 0, 0, 0);
            }
            __syncthreads();
        }

        // epilogue: C/D layout col=lane&15, row=(lane>>4)*4+q  [m89]
#pragma unroll
        for (int mi = 0; mi < 4; ++mi) {
#pragma unroll
            for (int qq = 0; qq < 4; ++qq) {
                int row = m0 + wm + mi * 16 + (l >> 4) * 4 + qq;
                if (GUARD && row >= Mreal) continue;
#pragma unroll
                for (int ni = 0; ni < 4; ++ni) {
                    int col = n0 + wn + ni * 16 + (l & 15);
                    if (GUARD && col >= Nreal) continue;
                    float v = acc[mi][ni][qq];
                    if (OUT_BF16) ((u16*)Cv)[(size_t)row * ldc + col] = f2bf(v);
                    else          ((float*)Cv)[(size_t)row * ldc + col] = v;
                }
            }
        }
    }
}

// ---------------- fused conv+GEMM1: xs1 = bf16(X) @ W1s^T, sd/ss = X.vd/vs ------
// Round-7 1-deep structure (measured best) + persistent grid (768 real = 3/CU
// exactly, striding over 940 virtual tiles -> no straggler round).
__global__ __launch_bounds__(256) void gemm_xw2(
    const float* __restrict__ X, const u16* __restrict__ Bw, u16* __restrict__ C,
    const float* __restrict__ vd, const float* __restrict__ vs,
    float* __restrict__ sd, float* __restrict__ ss)
{
    __shared__ u16 As[128 * 64];
    __shared__ u16 Bs[2][128 * 64];
    const int t = threadIdx.x;
    const int w = t >> 6, l = t & 63;
    const int wm = (w >> 1) * 64, wn = (w & 1) * 64;
    const int srow = w << 5;
    const int lrow = l >> 3, lc = l & 7;

    const int VGX = 4, NWG = 4 * 235;
    const int q = NWG >> 3, r = NWG & 7;

    for (int vb = blockIdx.x; vb < NWG; vb += gridDim.x) {
        const int xcd = vb & 7, loc = vb >> 3;
        const int swz = (xcd < r ? xcd * (q + 1) : r * (q + 1) + (xcd - r) * q) + loc;
        const int bx = swz % VGX, by = swz / VGX;
        const int m0 = by * 128, n0 = bx * 128;

        f32x4 acc[4][4] = {};
        float sdp[4] = {}, ssp[4] = {};
        const bool do_s = (bx == 0);

        int rowg[4];
        bool okr[4];
#pragma unroll
        for (int i = 0; i < 4; ++i) {
            rowg[i] = m0 + srow + i * 8 + lrow;
            okr[i] = rowg[i] < 30000;
        }

        float4 pa[4][2];
        auto loadA = [&](int kt) {
            int c = kt + lc * 8;
            bool okc = c < 3000;
#pragma unroll
            for (int i = 0; i < 4; ++i) {
                bool ok = okr[i] && okc;
                const float* p = X + (ok ? ((size_t)rowg[i] * 3000 + c) : 0);
                float4 v0 = *(const float4*)p;
                float4 v1 = *(const float4*)(p + 4);
                if (!ok) { v0 = make_float4(0.f, 0.f, 0.f, 0.f); v1 = v0; }
                pa[i][0] = v0;
                pa[i][1] = v1;
            }
        };
        auto stageB = [&](int kt2, int buf) {
#pragma unroll
            for (int i = 0; i < 4; ++i) {
                int row = srow + i * 8 + lrow;
                int gc = ((lc ^ (row & 7)) << 3);
                gload_lds16(Bw + (size_t)(n0 + row) * 3008 + kt2 + gc,
                            &Bs[buf][(srow + i * 8) * 64]);
            }
        };

        loadA(0);            // 8 vm
        stageB(0, 0);        // 4 vm
        int cur = 0;

        for (int kt = 0; kt < 3008; kt += 64) {
            if (do_s) {
                int c = kt + lc * 8;
                float4 d0 = *(const float4*)(vd + c);
                float4 d1 = *(const float4*)(vd + c + 4);
                float4 s0 = *(const float4*)(vs + c);
                float4 s1 = *(const float4*)(vs + c + 4);
#pragma unroll
                for (int i = 0; i < 4; ++i) {
                    sdp[i] += pa[i][0].x * d0.x + pa[i][0].y * d0.y + pa[i][0].z * d0.z + pa[i][0].w * d0.w
                            + pa[i][1].x * d1.x + pa[i][1].y * d1.y + pa[i][1].z * d1.z + pa[i][1].w * d1.w;
                    ssp[i] += pa[i][0].x * s0.x + pa[i][0].y * s0.y + pa[i][0].z * s0.z + pa[i][0].w * s0.w
                            + pa[i][1].x * s1.x + pa[i][1].y * s1.y + pa[i][1].z * s1.z + pa[i][1].w * s1.w;
                }
            }
            // convert current A -> As (swizzled); native casts -> cvt_pk
#pragma unroll
            for (int i = 0; i < 4; ++i) {
                int row = srow + i * 8 + lrow;
                bf16x8 o;
                o[0] = (bf16_t)pa[i][0].x; o[1] = (bf16_t)pa[i][0].y;
                o[2] = (bf16_t)pa[i][0].z; o[3] = (bf16_t)pa[i][0].w;
                o[4] = (bf16_t)pa[i][1].x; o[5] = (bf16_t)pa[i][1].y;
                o[6] = (bf16_t)pa[i][1].z; o[7] = (bf16_t)pa[i][1].w;
                *(bf16x8*)&As[row * 64 + ((lc ^ (row & 7)) << 3)] = o;
            }
            // prefetch next: A -> regs (8), B -> other buffer (4); always 12 ops
            loadA(kt + 64);
            int ktn = (kt + 64 < 3008) ? kt + 64 : 2944;
            stageB(ktn, cur ^ 1);
            // drain everything older than the 12 just-issued prefetch ops
            asm volatile("s_waitcnt vmcnt(12) lgkmcnt(0)" ::: "memory");
            __builtin_amdgcn_s_barrier();

#pragma unroll
            for (int kk = 0; kk < 2; ++kk) {
                bf16x8 af[4], bfr[4];
                int kc = kk * 4 + (l >> 4);
#pragma unroll
                for (int mi = 0; mi < 4; ++mi) {
                    int row = wm + mi * 16 + (l & 15);
                    af[mi] = *(const bf16x8*)&As[row * 64 + ((kc ^ (row & 7)) << 3)];
                }
#pragma unroll
                for (int ni = 0; ni < 4; ++ni) {
                    int col = wn + ni * 16 + (l & 15);
                    bfr[ni] = *(const bf16x8*)&Bs[cur][col * 64 + ((kc ^ (col & 7)) << 3)];
                }
#pragma unroll
                for (int mi = 0; mi < 4; ++mi)
#pragma unroll
                    for (int ni = 0; ni < 4; ++ni)
                        acc[mi][ni] = __builtin_amdgcn_mfma_f32_16x16x32_bf16(
                            af[mi], bfr[ni], acc[mi][ni], 0, 0, 0);
            }
            asm volatile("s_barrier" ::: "memory");
            cur ^= 1;
        }

        if (do_s) {
#pragma unroll
            for (int i = 0; i < 4; ++i) {
                float a = sdp[i], b = ssp[i];
                a += __shfl_xor(a, 1); a += __shfl_xor(a, 2); a += __shfl_xor(a, 4);
                b += __shfl_xor(b, 1); b += __shfl_xor(b, 2); b += __shfl_xor(b, 4);
                if (lc == 0 && okr[i]) { sd[rowg[i]] = a; ss[rowg[i]] = b; }
            }
        }

#pragma unroll
        for (int mi = 0; mi < 4; ++mi)
#pragma unroll
            for (int qq = 0; qq < 4; ++qq) {
                int row = m0 + wm + mi * 16 + (l >> 4) * 4 + qq;
#pragma unroll
                for (int ni = 0; ni < 4; ++ni) {
                    int col = n0 + wn + ni * 16 + (l & 15);
                    C[(size_t)row * 512 + col] = f2bf(acc[mi][ni][qq]);
                }
            }
    }
}

// ---------------- merged prep: vd/vs | w1sb | w1st | w2b | deg ----------------
__global__ void k_prep(const float* __restrict__ W1d, const float* __restrict__ a1d,
                       const float* __restrict__ W1s, const float* __restrict__ a1s,
                       const float* __restrict__ W2s, const int* __restrict__ dst,
                       float* __restrict__ vd, float* __restrict__ vs,
                       u16* __restrict__ w1sb, u16* __restrict__ w1st,
                       u16* __restrict__ w2sb, unsigned* __restrict__ deg) {
    int b = blockIdx.x, t = threadIdx.x;
    if (b < 12) {
        int i = b * 256 + t;
        if (i >= 3000) {
            if (i < 3008) { vd[i] = 0.f; vs[i] = 0.f; }   // zero K-pad
            return;
        }
        float ad = 0.f, as = 0.f;
        for (int h = 0; h < 512; ++h) {
            ad += W1d[(size_t)h * 3000 + i] * a1d[h];
            as += W1s[(size_t)h * 3000 + i] * a1s[h];
        }
        vd[i] = ad;
        vs[i] = as;
    } else if (b < 1516) {
        int idx = (b - 12) * 256 + t;          // 512*752
        int n = idx / 752, k = (idx % 752) * 4;
        ushort4 o = make_ushort4(0, 0, 0, 0);
        if (k < 3000) {
            float4 v = *(const float4*)(W1s + (size_t)n * 3000 + k);
            o.x = f2bf(v.x); o.y = f2bf(v.y); o.z = f2bf(v.z); o.w = f2bf(v.w);
        }
        *(ushort4*)(w1sb + (size_t)n * 3008 + k) = o;
    } else if (b < 1900) {
        __shared__ float tile[64][65];
        int fb = b - 1516;
        int i0 = (fb % 48) * 64, h0 = (fb / 48) * 64;
        int il = t & 63, hq = t >> 6;
#pragma unroll
        for (int rr = 0; rr < 16; ++rr) {
            int hl = rr * 4 + hq;
            int i = i0 + il;
            tile[hl][il] = (i < 3000) ? W1s[(size_t)(h0 + hl) * 3000 + i] : 0.f;
        }
        __syncthreads();
#pragma unroll
        for (int rr = 0; rr < 16; ++rr) {
            int il2 = rr * 4 + hq;
            w1st[(size_t)(i0 + il2) * 512 + h0 + il] = f2bf(tile[il][il2]);
        }
    } else if (b < 2156) {
        int idx = (b - 1900) * 256 + t;        // 128*512
        int n = idx >> 9, k = idx & 511;
        w2sb[idx] = (n < 30) ? f2bf(W2s[(size_t)n * 512 + k]) : (u16)0;
    } else {
        int j = (b - 2156) * 256 + t;
        if (j < 180000) atomicAdd(&deg[dst[j]], 1u);
    }
}

// ---------------- scan stage 1: per-block sums ----------------
__global__ void k_scan1(const unsigned* __restrict__ deg, unsigned* __restrict__ bsum, int n) {
    __shared__ unsigned ws[4];
    int i = blockIdx.x * 256 + threadIdx.x;
    unsigned v = (i < n) ? deg[i] : 0u;
#pragma unroll
    for (int s = 32; s; s >>= 1) v += __shfl_xor(v, s);
    if ((threadIdx.x & 63) == 0) ws[threadIdx.x >> 6] = v;
    __syncthreads();
    if (threadIdx.x == 0) bsum[blockIdx.x] = ws[0] + ws[1] + ws[2] + ws[3];
}

// ---------------- scan stage 2: per-block offset via masked wave-sum + local scan --
__global__ void k_scanB(const unsigned* __restrict__ deg, const unsigned* __restrict__ bsum,
                        unsigned* __restrict__ off, unsigned* __restrict__ cur,
                        int n, int nb) {
    __shared__ unsigned tmp[256];
    __shared__ unsigned bo;
    int b = blockIdx.x, t = threadIdx.x, i = b * 256 + t;
    if (t < 64) {
        unsigned s0 = (t < nb) ? bsum[t] : 0u;
        unsigned s1 = (t + 64 < nb) ? bsum[t + 64] : 0u;
        unsigned v = ((t < b) ? s0 : 0u) + ((t + 64 < b) ? s1 : 0u);
#pragma unroll
        for (int s = 32; s; s >>= 1) v += __shfl_xor(v, s);
        if (t == 0) bo = v;
        if (b == nb - 1) {
            unsigned tv = s0 + s1;
#pragma unroll
            for (int s = 32; s; s >>= 1) tv += __shfl_xor(tv, s);
            if (t == 0) off[n] = tv;
        }
    }
    __syncthreads();
    unsigned v = (i < n) ? deg[i] : 0u;
    tmp[t] = v;
    __syncthreads();
    for (int s = 1; s < 256; s <<= 1) {
        unsigned a = (t >= s) ? tmp[t - s] : 0u;
        __syncthreads();
        tmp[t] += a;
        __syncthreads();
    }
    if (i < n) {
        unsigned o = bo + tmp[t] - v;
        off[i] = o;
        cur[i] = o;
    }
}

__global__ void k_fill(const int* __restrict__ dst, unsigned* __restrict__ cur,
                       unsigned* __restrict__ csr) {
    int j = blockIdx.x * 256 + threadIdx.x;
    if (j >= 180000) return;
    unsigned pos = atomicAdd(&cur[dst[j]], 1u);
    csr[pos] = (unsigned)j;
}

// ---------------- fused score+softmax: alpha from ss/sd, 8-lane groups ----------
__global__ void k_soft(const int* __restrict__ src, const float* __restrict__ ss,
                       const float* __restrict__ sd, float* __restrict__ alpha,
                       const unsigned* __restrict__ csr, const unsigned* __restrict__ off) {
    int t = threadIdx.x;
    int g = t >> 3, l = t & 7;
    int n = blockIdx.x * 32 + g;
    if (n >= 30000) return;
    unsigned lo = off[n], hi = off[n + 1];
    if (lo == hi) return;
    float sdn = sd[n];
    float m = -1e30f;
    for (unsigned i = lo + l; i < hi; i += 8) {
        float v = ss[src[csr[i]]] + sdn;
        v = v > 0.f ? v : 0.2f * v;
        m = fmaxf(m, v);
    }
    m = fmaxf(m, __shfl_xor(m, 1));
    m = fmaxf(m, __shfl_xor(m, 2));
    m = fmaxf(m, __shfl_xor(m, 4));
    float den = 0.f;
    for (unsigned i = lo + l; i < hi; i += 8) {
        float v = ss[src[csr[i]]] + sdn;
        v = v > 0.f ? v : 0.2f * v;
        den += expf(v - m);
    }
    den += __shfl_xor(den, 1);
    den += __shfl_xor(den, 2);
    den += __shfl_xor(den, 4);
    float inv = 1.f / den;
    for (unsigned i = lo + l; i < hi; i += 8) {
        unsigned j = csr[i];
        float v = ss[src[j]] + sdn;
        v = v > 0.f ? v : 0.2f * v;
        alpha[j] = expf(v - m) * inv;
    }
}

// ---------------- aggregation + ELU: wave per node, 2-edge pipelined gathers ------
__global__ void k_agg(const u16* __restrict__ xin, const float* __restrict__ alpha,
                      const unsigned* __restrict__ csr, const unsigned* __restrict__ off,
                      const int* __restrict__ src, u16* __restrict__ outb, int nvalid) {
    int w = threadIdx.x >> 6, l = threadIdx.x & 63;
    int n = blockIdx.x * 4 + w;
    float acc[8] = {};
    if (n < nvalid) {
        unsigned lo = off[n], hi = off[n + 1];
        unsigned i = lo;
        for (; i + 2 <= hi; i += 2) {
            unsigned j0 = csr[i], j1 = csr[i + 1];
            float a0 = alpha[j0], a1 = alpha[j1];
            int s0 = src[j0], s1 = src[j1];
            u16x8 r0 = *(const u16x8*)&xin[(size_t)s0 * 512 + l * 8];
            u16x8 r1 = *(const u16x8*)&xin[(size_t)s1 * 512 + l * 8];
#pragma unroll
            for (int k = 0; k < 8; ++k) acc[k] += a0 * bf2f(r0[k]) + a1 * bf2f(r1[k]);
        }
        if (i < hi) {
            unsigned j0 = csr[i];
            float a0 = alpha[j0];
            int s0 = src[j0];
            u16x8 r0 = *(const u16x8*)&xin[(size_t)s0 * 512 + l * 8];
#pragma unroll
            for (int k = 0; k < 8; ++k) acc[k] += a0 * bf2f(r0[k]);
        }
    }
    u16x8 o;
#pragma unroll
    for (int k = 0; k < 8; ++k) {
        float a = acc[k] > 0.f ? acc[k] : expf(acc[k]) - 1.f;
        o[k] = f2bf(a);
    }
    *(u16x8*)&outb[(size_t)n * 512 + l * 8] = o;
}

// ---------------- aggG: g[n,:] = sum alpha_e * h2[src_e,:]  (30-wide fp32) -------
__global__ void k_aggG(const float* __restrict__ h2, const float* __restrict__ alpha,
                       const unsigned* __restrict__ csr, const unsigned* __restrict__ off,
                       const int* __restrict__ src, float* __restrict__ g) {
    int t = threadIdx.x, grp = t >> 3, l = t & 7;
    int n = blockIdx.x * 32 + grp;
    if (n >= 30000) return;
    unsigned lo = off[n], hi = off[n + 1];
    float acc[4] = {};
    int c0 = l * 4;
    for (unsigned i = lo; i < hi; ++i) {
        unsigned j = csr[i];
        float a = alpha[j];
        const float* row = h2 + (size_t)src[j] * 30;
#pragma unroll
        for (int k = 0; k < 4; ++k) {
            int c = c0 + k;
            if (c < 30) acc[k] += a * row[c];
        }
    }
#pragma unroll
    for (int k = 0; k < 4; ++k) {
        int c = c0 + k;
        if (c < 30) g[(size_t)n * 30 + c] = acc[k];
    }
}

// ---------------- h3[n,:] = elu(g[n,:] @ W2s)  -> bf16 [30080][512] -------------
__global__ void k_h3(const float* __restrict__ g, const float* __restrict__ W2s,
                     u16* __restrict__ h3b) {
    int t = threadIdx.x;
    size_t n0 = (size_t)blockIdx.x * 8;
    float w0[30], w1[30];
#pragma unroll
    for (int o = 0; o < 30; ++o) {
        w0[o] = W2s[(size_t)o * 512 + t];
        w1[o] = W2s[(size_t)o * 512 + t + 256];
    }
    for (int rr = 0; rr < 8; ++rr) {
        size_t n = n0 + rr;
        float a0 = 0.f, a1 = 0.f;
        if (n < 30000) {
            const float* gr = g + n * 30;
#pragma unroll
            for (int o = 0; o < 30; ++o) {
                float v = gr[o];
                a0 += v * w0[o];
                a1 += v * w1[o];
            }
            a0 = a0 > 0.f ? a0 : expf(a0) - 1.f;
            a1 = a1 > 0.f ? a1 : expf(a1) - 1.f;
        }
        h3b[n * 512 + t] = f2bf(a0);
        h3b[n * 512 + t + 256] = f2bf(a1);
    }
}

extern "C" void kernel_launch(void* const* d_in, const int* in_sizes, int n_in,
                              void* d_out, int out_size, void* d_ws, size_t ws_size,
                              hipStream_t stream) {
    const float* X   = (const float*)d_in[0];
    const int*   ei  = (const int*)d_in[1];
    const float* W1s = (const float*)d_in[2];
    const float* W1d = (const float*)d_in[3];
    const float* a1s = (const float*)d_in[4];
    const float* a1d = (const float*)d_in[5];
    const float* W2s = (const float*)d_in[6];
    const int* src = ei;
    const int* dst = ei + 180000;

    float* out = (float*)d_out;
    float* h2 = out;               // [30000][30]
    float* h4 = out + 900000;      // [30000][3000]

    // scratch inside d_out h4 region (dead before gemm5 overwrites it)
    char* ob = (char*)(out + 900000);
    u16* xs1b = (u16*)ob;                                  // 30080*512
    u16* h1b  = (u16*)(ob + 30801920);                     // 30080*512
    float* g  = (float*)(ob + 30801920 + 30801920);        // 30000*30 fp32

    // ws scratch (must survive gemm5): h3b + W1sT + small vectors
    char* w = (char*)d_ws;
    auto carve = [&](size_t bytes) { char* p = w; w += (bytes + 255) & ~(size_t)255; return p; };
    u16* w1sb  = (u16*)carve((size_t)512 * 3008 * 2);
    u16* w1st  = (u16*)carve((size_t)3072 * 512 * 2);
    u16* w2sb  = (u16*)carve((size_t)128 * 512 * 2);
    u16* h3b   = (u16*)carve((size_t)30080 * 512 * 2);
    float* vd    = (float*)carve(3008 * 4);
    float* vs    = (float*)carve(3008 * 4);
    float* ss    = (float*)carve(30000 * 4);
    float* sd    = (float*)carve(30000 * 4);
    float* alpha = (float*)carve(180000 * 4);
    unsigned* deg = (unsigned*)carve(30000 * 4);
    unsigned* off = (unsigned*)carve(30004 * 4);
    unsigned* cur = (unsigned*)carve(30000 * 4);
    unsigned* csr = (unsigned*)carve(180000 * 4);
    unsigned* bsum = (unsigned*)carve(128 * 4);

    hipMemsetAsync(deg, 0, 30000 * 4, stream);

    // merged prep: vd/vs | w1sb | w1st | w2sb | deg
    k_prep<<<2860, 256, 0, stream>>>(W1d, a1d, W1s, a1s, W2s, dst,
                                     vd, vs, w1sb, w1st, w2sb, deg);

    // fused: xs1 = bf16(X) @ W1s^T + sd/ss. Persistent: 768 blocks (3/CU) over 940 tiles.
    gemm_xw2<<<768, 256, 0, stream>>>(X, w1sb, xs1b, vd, vs, sd, ss);

    k_scan1<<<118, 256, 0, stream>>>(deg, bsum, 30000);
    k_scanB<<<118, 256, 0, stream>>>(deg, bsum, off, cur, 30000, 118);
    k_fill<<<704, 256, 0, stream>>>(dst, cur, csr);
    k_soft<<<938, 256, 0, stream>>>(src, ss, sd, alpha, csr, off);

    k_agg <<<7520, 256, 0, stream>>>(xs1b, alpha, csr, off, src, h1b, 30000);

    // h2 = h1 @ W2s.T via MFMA (235 tiles, non-persistent)
    gemm_bt<false, true><<<235, 256, 0, stream>>>(h1b, w2sb, h2, 512, 30, 30000, 30, 1, 235);

    // g = agg(alpha, h2);  h3 = elu(g @ W2s)   [agg commutes with linear map]
    k_aggG<<<938, 256, 0, stream>>>(h2, alpha, csr, off, src, g);
    k_h3 <<<3760, 256, 0, stream>>>(g, W2s, h3b);

    // gemm5: persistent 1280 blocks (5/CU at 32KB LDS) over 5640 tiles
    gemm_bt<false, true><<<1280, 256, 0, stream>>>(h3b, w1st, h4, 512, 3000, 30000, 3000, 24, 235);
}

// Round 13
// 591.074 us; speedup vs baseline: 1.1785x; 1.0840x over previous
//
#include <hip/hip_runtime.h>

typedef unsigned short u16;
typedef __bf16 bf16_t;
typedef bf16_t bf16x8 __attribute__((ext_vector_type(8)));
typedef float f32x4 __attribute__((ext_vector_type(4)));
typedef u16 u16x8 __attribute__((ext_vector_type(8)));

#define AS1 __attribute__((address_space(1)))
#define AS3 __attribute__((address_space(3)))

__device__ __forceinline__ u16 f2bf(float f) {
    union { float f; unsigned u; } v; v.f = f;
    unsigned r = v.u + 0x7FFFu + ((v.u >> 16) & 1u);
    return (u16)(r >> 16);
}
__device__ __forceinline__ float bf2f(u16 s) {
    union { unsigned u; float f; } v; v.u = ((unsigned)s) << 16;
    return v.f;
}

__device__ __forceinline__ void gload_lds16(const u16* g, u16* l) {
    __builtin_amdgcn_global_load_lds((AS1 const void*)g, (AS3 void*)l, 16, 0, 0);
}

// ---------------- big GEMM: C[M,N] = A[M,K] * B[N,K]^T, bf16 in, 128x128 tile ----
// Flat persistent grid: real blocks grid-stride over vgx*vgy virtual tiles.
template <bool OUT_BF16, bool GUARD>
__global__ __launch_bounds__(256) void gemm_bt(
    const u16* __restrict__ A, const u16* __restrict__ B, void* __restrict__ Cv,
    int K, int ldc, int Mreal, int Nreal, int vgx, int vgy)
{
    __shared__ u16 As[128 * 64];
    __shared__ u16 Bs[128 * 64];
    const int t = threadIdx.x;
    const int w = t >> 6, l = t & 63;
    const int wm = (w >> 1) * 64, wn = (w & 1) * 64;
    const int srow = w << 5;
    const int lrow = l >> 3, lc = l & 7;
    const int nwg = vgx * vgy;
    const int q = nwg >> 3, r = nwg & 7;

    for (int vb = blockIdx.x; vb < nwg; vb += gridDim.x) {
        const int xcd = vb & 7, loc = vb >> 3;
        const int swz = (xcd < r ? xcd * (q + 1) : r * (q + 1) + (xcd - r) * q) + loc;
        const int bx = swz % vgx, by = swz / vgx;
        const int m0 = by * 128, n0 = bx * 128;

        f32x4 acc[4][4] = {};

        for (int kt = 0; kt < K; kt += 64) {
#pragma unroll
            for (int i = 0; i < 4; ++i) {
                int row = srow + i * 8 + lrow;
                int gc = ((lc ^ (row & 7)) << 3);
                const u16* ga = A + (size_t)(m0 + row) * K + kt + gc;
                const u16* gb = B + (size_t)(n0 + row) * K + kt + gc;
                gload_lds16(ga, &As[(srow + i * 8) * 64]);
                gload_lds16(gb, &Bs[(srow + i * 8) * 64]);
            }
            asm volatile("s_waitcnt vmcnt(0)");
            __syncthreads();

#pragma unroll
            for (int kk = 0; kk < 2; ++kk) {
                bf16x8 af[4], bfr[4];
                int kc = kk * 4 + (l >> 4);
#pragma unroll
                for (int mi = 0; mi < 4; ++mi) {
                    int row = wm + mi * 16 + (l & 15);
                    af[mi] = *(const bf16x8*)&As[row * 64 + ((kc ^ (row & 7)) << 3)];
                }
#pragma unroll
                for (int ni = 0; ni < 4; ++ni) {
                    int col = wn + ni * 16 + (l & 15);
                    bfr[ni] = *(const bf16x8*)&Bs[col * 64 + ((kc ^ (col & 7)) << 3)];
                }
#pragma unroll
                for (int mi = 0; mi < 4; ++mi)
#pragma unroll
                    for (int ni = 0; ni < 4; ++ni)
                        acc[mi][ni] = __builtin_amdgcn_mfma_f32_16x16x32_bf16(
                            af[mi], bfr[ni], acc[mi][ni], 0, 0, 0);
            }
            __syncthreads();
        }

        // epilogue: C/D layout col=lane&15, row=(lane>>4)*4+q  [m89]
#pragma unroll
        for (int mi = 0; mi < 4; ++mi) {
#pragma unroll
            for (int qq = 0; qq < 4; ++qq) {
                int row = m0 + wm + mi * 16 + (l >> 4) * 4 + qq;
                if (GUARD && row >= Mreal) continue;
#pragma unroll
                for (int ni = 0; ni < 4; ++ni) {
                    int col = n0 + wn + ni * 16 + (l & 15);
                    if (GUARD && col >= Nreal) continue;
                    float v = acc[mi][ni][qq];
                    if (OUT_BF16) ((u16*)Cv)[(size_t)row * ldc + col] = f2bf(v);
                    else          ((float*)Cv)[(size_t)row * ldc + col] = v;
                }
            }
        }
    }
}

// ---------------- fused conv+GEMM1: round-10 form (PASSING, 258us) --------------
// 1-deep A reg prefetch, B double-buffered via gload_lds, both prefetches issued
// together then vmcnt(12) = "all but the 12 newest" -> order-robust (the 12
// newest ARE the prefetch regardless of interleave). Persistent 768 = 3/CU.
__global__ __launch_bounds__(256) void gemm_xw2(
    const float* __restrict__ X, const u16* __restrict__ Bw, u16* __restrict__ C,
    const float* __restrict__ vd, const float* __restrict__ vs,
    float* __restrict__ sd, float* __restrict__ ss)
{
    __shared__ u16 As[128 * 64];
    __shared__ u16 Bs[2][128 * 64];
    const int t = threadIdx.x;
    const int w = t >> 6, l = t & 63;
    const int wm = (w >> 1) * 64, wn = (w & 1) * 64;
    const int srow = w << 5;
    const int lrow = l >> 3, lc = l & 7;

    const int VGX = 4, NWG = 4 * 235;
    const int q = NWG >> 3, r = NWG & 7;

    for (int vb = blockIdx.x; vb < NWG; vb += gridDim.x) {
        const int xcd = vb & 7, loc = vb >> 3;
        const int swz = (xcd < r ? xcd * (q + 1) : r * (q + 1) + (xcd - r) * q) + loc;
        const int bx = swz % VGX, by = swz / VGX;
        const int m0 = by * 128, n0 = bx * 128;

        f32x4 acc[4][4] = {};
        float sdp[4] = {}, ssp[4] = {};
        const bool do_s = (bx == 0);

        int rowg[4];
        bool okr[4];
#pragma unroll
        for (int i = 0; i < 4; ++i) {
            rowg[i] = m0 + srow + i * 8 + lrow;
            okr[i] = rowg[i] < 30000;
        }

        float4 pa[4][2];
        auto loadA = [&](int kt) {
            int c = kt + lc * 8;
            bool okc = c < 3000;
#pragma unroll
            for (int i = 0; i < 4; ++i) {
                bool ok = okr[i] && okc;
                const float* p = X + (ok ? ((size_t)rowg[i] * 3000 + c) : 0);
                float4 v0 = *(const float4*)p;
                float4 v1 = *(const float4*)(p + 4);
                if (!ok) { v0 = make_float4(0.f, 0.f, 0.f, 0.f); v1 = v0; }
                pa[i][0] = v0;
                pa[i][1] = v1;
            }
        };
        auto stageB = [&](int kt2, int buf) {
#pragma unroll
            for (int i = 0; i < 4; ++i) {
                int row = srow + i * 8 + lrow;
                int gc = ((lc ^ (row & 7)) << 3);
                gload_lds16(Bw + (size_t)(n0 + row) * 3008 + kt2 + gc,
                            &Bs[buf][(srow + i * 8) * 64]);
            }
        };

        loadA(0);            // 8 vm
        stageB(0, 0);        // 4 vm
        int cur = 0;

        for (int kt = 0; kt < 3008; kt += 64) {
            if (do_s) {
                int c = kt + lc * 8;
                float4 d0 = *(const float4*)(vd + c);
                float4 d1 = *(const float4*)(vd + c + 4);
                float4 s0 = *(const float4*)(vs + c);
                float4 s1 = *(const float4*)(vs + c + 4);
#pragma unroll
                for (int i = 0; i < 4; ++i) {
                    sdp[i] += pa[i][0].x * d0.x + pa[i][0].y * d0.y + pa[i][0].z * d0.z + pa[i][0].w * d0.w
                            + pa[i][1].x * d1.x + pa[i][1].y * d1.y + pa[i][1].z * d1.z + pa[i][1].w * d1.w;
                    ssp[i] += pa[i][0].x * s0.x + pa[i][0].y * s0.y + pa[i][0].z * s0.z + pa[i][0].w * s0.w
                            + pa[i][1].x * s1.x + pa[i][1].y * s1.y + pa[i][1].z * s1.z + pa[i][1].w * s1.w;
                }
            }
            // convert current A -> As (swizzled); native casts -> cvt_pk
#pragma unroll
            for (int i = 0; i < 4; ++i) {
                int row = srow + i * 8 + lrow;
                bf16x8 o;
                o[0] = (bf16_t)pa[i][0].x; o[1] = (bf16_t)pa[i][0].y;
                o[2] = (bf16_t)pa[i][0].z; o[3] = (bf16_t)pa[i][0].w;
                o[4] = (bf16_t)pa[i][1].x; o[5] = (bf16_t)pa[i][1].y;
                o[6] = (bf16_t)pa[i][1].z; o[7] = (bf16_t)pa[i][1].w;
                *(bf16x8*)&As[row * 64 + ((lc ^ (row & 7)) << 3)] = o;
            }
            // prefetch next: A -> regs (8), B -> other buffer (4); always 12 ops
            loadA(kt + 64);
            int ktn = (kt + 64 < 3008) ? kt + 64 : 2944;
            stageB(ktn, cur ^ 1);
            // drain everything older than the 12 just-issued prefetch ops
            asm volatile("s_waitcnt vmcnt(12) lgkmcnt(0)" ::: "memory");
            __builtin_amdgcn_s_barrier();

#pragma unroll
            for (int kk = 0; kk < 2; ++kk) {
                bf16x8 af[4], bfr[4];
                int kc = kk * 4 + (l >> 4);
#pragma unroll
                for (int mi = 0; mi < 4; ++mi) {
                    int row = wm + mi * 16 + (l & 15);
                    af[mi] = *(const bf16x8*)&As[row * 64 + ((kc ^ (row & 7)) << 3)];
                }
#pragma unroll
                for (int ni = 0; ni < 4; ++ni) {
                    int col = wn + ni * 16 + (l & 15);
                    bfr[ni] = *(const bf16x8*)&Bs[cur][col * 64 + ((kc ^ (col & 7)) << 3)];
                }
#pragma unroll
                for (int mi = 0; mi < 4; ++mi)
#pragma unroll
                    for (int ni = 0; ni < 4; ++ni)
                        acc[mi][ni] = __builtin_amdgcn_mfma_f32_16x16x32_bf16(
                            af[mi], bfr[ni], acc[mi][ni], 0, 0, 0);
            }
            asm volatile("s_barrier" ::: "memory");
            cur ^= 1;
        }

        if (do_s) {
#pragma unroll
            for (int i = 0; i < 4; ++i) {
                float a = sdp[i], b = ssp[i];
                a += __shfl_xor(a, 1); a += __shfl_xor(a, 2); a += __shfl_xor(a, 4);
                b += __shfl_xor(b, 1); b += __shfl_xor(b, 2); b += __shfl_xor(b, 4);
                if (lc == 0 && okr[i]) { sd[rowg[i]] = a; ss[rowg[i]] = b; }
            }
        }

#pragma unroll
        for (int mi = 0; mi < 4; ++mi)
#pragma unroll
            for (int qq = 0; qq < 4; ++qq) {
                int row = m0 + wm + mi * 16 + (l >> 4) * 4 + qq;
#pragma unroll
                for (int ni = 0; ni < 4; ++ni) {
                    int col = n0 + wn + ni * 16 + (l & 15);
                    C[(size_t)row * 512 + col] = f2bf(acc[mi][ni][qq]);
                }
            }
    }
}

// ---------------- merged prep: vd/vs partials | w1sb | w1st | w2b | deg ----------
// S0 [0,48): vd/vs 4-way h-split partials (256-iter latency chains, was 512x2)
// S1 [48,1552): W1s->bf16 [512][3008]   S2 [1552,1936): W1s^T tiled
// S3 [1936,2192): W2s->bf16 [128][512]  S4 [2192,2896): deg atomics
__global__ void k_prep(const float* __restrict__ W1d, const float* __restrict__ a1d,
                       const float* __restrict__ W1s, const float* __restrict__ a1s,
                       const float* __restrict__ W2s, const int* __restrict__ dst,
                       float* __restrict__ vdp, float* __restrict__ vsp,
                       u16* __restrict__ w1sb, u16* __restrict__ w1st,
                       u16* __restrict__ w2sb, unsigned* __restrict__ deg) {
    int b = blockIdx.x, t = threadIdx.x;
    if (b < 48) {
        int hseg = b & 3, iblk = b >> 2;
        int i = iblk * 256 + t;
        if (i >= 3000) return;
        float ad = 0.f, as = 0.f;
        int h0 = hseg * 128;
        for (int h = h0; h < h0 + 128; ++h) {
            ad += W1d[(size_t)h * 3000 + i] * a1d[h];
            as += W1s[(size_t)h * 3000 + i] * a1s[h];
        }
        vdp[(size_t)hseg * 3008 + i] = ad;
        vsp[(size_t)hseg * 3008 + i] = as;
    } else if (b < 1552) {
        int idx = (b - 48) * 256 + t;          // 512*752
        int n = idx / 752, k = (idx % 752) * 4;
        ushort4 o = make_ushort4(0, 0, 0, 0);
        if (k < 3000) {
            float4 v = *(const float4*)(W1s + (size_t)n * 3000 + k);
            o.x = f2bf(v.x); o.y = f2bf(v.y); o.z = f2bf(v.z); o.w = f2bf(v.w);
        }
        *(ushort4*)(w1sb + (size_t)n * 3008 + k) = o;
    } else if (b < 1936) {
        __shared__ float tile[64][65];
        int fb = b - 1552;
        int i0 = (fb % 48) * 64, h0 = (fb / 48) * 64;
        int il = t & 63, hq = t >> 6;
#pragma unroll
        for (int rr = 0; rr < 16; ++rr) {
            int hl = rr * 4 + hq;
            int i = i0 + il;
            tile[hl][il] = (i < 3000) ? W1s[(size_t)(h0 + hl) * 3000 + i] : 0.f;
        }
        __syncthreads();
#pragma unroll
        for (int rr = 0; rr < 16; ++rr) {
            int il2 = rr * 4 + hq;
            w1st[(size_t)(i0 + il2) * 512 + h0 + il] = f2bf(tile[il][il2]);
        }
    } else if (b < 2192) {
        int idx = (b - 1936) * 256 + t;        // 128*512
        int n = idx >> 9, k = idx & 511;
        w2sb[idx] = (n < 30) ? f2bf(W2s[(size_t)n * 512 + k]) : (u16)0;
    } else {
        int j = (b - 2192) * 256 + t;
        if (j < 180000) atomicAdd(&deg[dst[j]], 1u);
    }
}

// ---------------- combine vd/vs partials (deterministic, no atomics) -----------
__global__ void k_comb(const float* __restrict__ vdp, const float* __restrict__ vsp,
                       float* __restrict__ vd, float* __restrict__ vs) {
    int i = blockIdx.x * 256 + threadIdx.x;
    if (i >= 3008) return;
    if (i < 3000) {
        vd[i] = vdp[i] + vdp[3008 + i] + vdp[6016 + i] + vdp[9024 + i];
        vs[i] = vsp[i] + vsp[3008 + i] + vsp[6016 + i] + vsp[9024 + i];
    } else {
        vd[i] = 0.f;   // zero K-pad (gemm_xw2 reads up to 3008)
        vs[i] = 0.f;
    }
}

// ---------------- scan stage 1: per-block sums ----------------
__global__ void k_scan1(const unsigned* __restrict__ deg, unsigned* __restrict__ bsum, int n) {
    __shared__ unsigned ws[4];
    int i = blockIdx.x * 256 + threadIdx.x;
    unsigned v = (i < n) ? deg[i] : 0u;
#pragma unroll
    for (int s = 32; s; s >>= 1) v += __shfl_xor(v, s);
    if ((threadIdx.x & 63) == 0) ws[threadIdx.x >> 6] = v;
    __syncthreads();
    if (threadIdx.x == 0) bsum[blockIdx.x] = ws[0] + ws[1] + ws[2] + ws[3];
}

// ---------------- scan stage 2: per-block offset via masked wave-sum + local scan --
__global__ void k_scanB(const unsigned* __restrict__ deg, const unsigned* __restrict__ bsum,
                        unsigned* __restrict__ off, unsigned* __restrict__ cur,
                        int n, int nb) {
    __shared__ unsigned tmp[256];
    __shared__ unsigned bo;
    int b = blockIdx.x, t = threadIdx.x, i = b * 256 + t;
    if (t < 64) {
        unsigned s0 = (t < nb) ? bsum[t] : 0u;
        unsigned s1 = (t + 64 < nb) ? bsum[t + 64] : 0u;
        unsigned v = ((t < b) ? s0 : 0u) + ((t + 64 < b) ? s1 : 0u);
#pragma unroll
        for (int s = 32; s; s >>= 1) v += __shfl_xor(v, s);
        if (t == 0) bo = v;
        if (b == nb - 1) {
            unsigned tv = s0 + s1;
#pragma unroll
            for (int s = 32; s; s >>= 1) tv += __shfl_xor(tv, s);
            if (t == 0) off[n] = tv;
        }
    }
    __syncthreads();
    unsigned v = (i < n) ? deg[i] : 0u;
    tmp[t] = v;
    __syncthreads();
    for (int s = 1; s < 256; s <<= 1) {
        unsigned a = (t >= s) ? tmp[t - s] : 0u;
        __syncthreads();
        tmp[t] += a;
        __syncthreads();
    }
    if (i < n) {
        unsigned o = bo + tmp[t] - v;
        off[i] = o;
        cur[i] = o;
    }
}

__global__ void k_fill(const int* __restrict__ dst, unsigned* __restrict__ cur,
                       unsigned* __restrict__ csr) {
    int j = blockIdx.x * 256 + threadIdx.x;
    if (j >= 180000) return;
    unsigned pos = atomicAdd(&cur[dst[j]], 1u);
    csr[pos] = (unsigned)j;
}

// ---------------- fused score+softmax: alpha from ss/sd, 8-lane groups ----------
__global__ void k_soft(const int* __restrict__ src, const float* __restrict__ ss,
                       const float* __restrict__ sd, float* __restrict__ alpha,
                       const unsigned* __restrict__ csr, const unsigned* __restrict__ off) {
    int t = threadIdx.x;
    int g = t >> 3, l = t & 7;
    int n = blockIdx.x * 32 + g;
    if (n >= 30000) return;
    unsigned lo = off[n], hi = off[n + 1];
    if (lo == hi) return;
    float sdn = sd[n];
    float m = -1e30f;
    for (unsigned i = lo + l; i < hi; i += 8) {
        float v = ss[src[csr[i]]] + sdn;
        v = v > 0.f ? v : 0.2f * v;
        m = fmaxf(m, v);
    }
    m = fmaxf(m, __shfl_xor(m, 1));
    m = fmaxf(m, __shfl_xor(m, 2));
    m = fmaxf(m, __shfl_xor(m, 4));
    float den = 0.f;
    for (unsigned i = lo + l; i < hi; i += 8) {
        float v = ss[src[csr[i]]] + sdn;
        v = v > 0.f ? v : 0.2f * v;
        den += expf(v - m);
    }
    den += __shfl_xor(den, 1);
    den += __shfl_xor(den, 2);
    den += __shfl_xor(den, 4);
    float inv = 1.f / den;
    for (unsigned i = lo + l; i < hi; i += 8) {
        unsigned j = csr[i];
        float v = ss[src[j]] + sdn;
        v = v > 0.f ? v : 0.2f * v;
        alpha[j] = expf(v - m) * inv;
    }
}

// ---------------- aggregation + ELU: wave per node, 2-edge pipelined gathers ------
__global__ void k_agg(const u16* __restrict__ xin, const float* __restrict__ alpha,
                      const unsigned* __restrict__ csr, const unsigned* __restrict__ off,
                      const int* __restrict__ src, u16* __restrict__ outb, int nvalid) {
    int w = threadIdx.x >> 6, l = threadIdx.x & 63;
    int n = blockIdx.x * 4 + w;
    float acc[8] = {};
    if (n < nvalid) {
        unsigned lo = off[n], hi = off[n + 1];
        unsigned i = lo;
        for (; i + 2 <= hi; i += 2) {
            unsigned j0 = csr[i], j1 = csr[i + 1];
            float a0 = alpha[j0], a1 = alpha[j1];
            int s0 = src[j0], s1 = src[j1];
            u16x8 r0 = *(const u16x8*)&xin[(size_t)s0 * 512 + l * 8];
            u16x8 r1 = *(const u16x8*)&xin[(size_t)s1 * 512 + l * 8];
#pragma unroll
            for (int k = 0; k < 8; ++k) acc[k] += a0 * bf2f(r0[k]) + a1 * bf2f(r1[k]);
        }
        if (i < hi) {
            unsigned j0 = csr[i];
            float a0 = alpha[j0];
            int s0 = src[j0];
            u16x8 r0 = *(const u16x8*)&xin[(size_t)s0 * 512 + l * 8];
#pragma unroll
            for (int k = 0; k < 8; ++k) acc[k] += a0 * bf2f(r0[k]);
        }
    }
    u16x8 o;
#pragma unroll
    for (int k = 0; k < 8; ++k) {
        float a = acc[k] > 0.f ? acc[k] : expf(acc[k]) - 1.f;
        o[k] = f2bf(a);
    }
    *(u16x8*)&outb[(size_t)n * 512 + l * 8] = o;
}

// ---------------- aggG: g[n,:] = sum alpha_e * h2[src_e,:]  (30-wide fp32) -------
__global__ void k_aggG(const float* __restrict__ h2, const float* __restrict__ alpha,
                       const unsigned* __restrict__ csr, const unsigned* __restrict__ off,
                       const int* __restrict__ src, float* __restrict__ g) {
    int t = threadIdx.x, grp = t >> 3, l = t & 7;
    int n = blockIdx.x * 32 + grp;
    if (n >= 30000) return;
    unsigned lo = off[n], hi = off[n + 1];
    float acc[4] = {};
    int c0 = l * 4;
    for (unsigned i = lo; i < hi; ++i) {
        unsigned j = csr[i];
        float a = alpha[j];
        const float* row = h2 + (size_t)src[j] * 30;
#pragma unroll
        for (int k = 0; k < 4; ++k) {
            int c = c0 + k;
            if (c < 30) acc[k] += a * row[c];
        }
    }
#pragma unroll
    for (int k = 0; k < 4; ++k) {
        int c = c0 + k;
        if (c < 30) g[(size_t)n * 30 + c] = acc[k];
    }
}

// ---------------- h3[n,:] = elu(g[n,:] @ W2s)  -> bf16 [30080][512] -------------
__global__ void k_h3(const float* __restrict__ g, const float* __restrict__ W2s,
                     u16* __restrict__ h3b) {
    int t = threadIdx.x;
    size_t n0 = (size_t)blockIdx.x * 8;
    float w0[30], w1[30];
#pragma unroll
    for (int o = 0; o < 30; ++o) {
        w0[o] = W2s[(size_t)o * 512 + t];
        w1[o] = W2s[(size_t)o * 512 + t + 256];
    }
    for (int rr = 0; rr < 8; ++rr) {
        size_t n = n0 + rr;
        float a0 = 0.f, a1 = 0.f;
        if (n < 30000) {
            const float* gr = g + n * 30;
#pragma unroll
            for (int o = 0; o < 30; ++o) {
                float v = gr[o];
                a0 += v * w0[o];
                a1 += v * w1[o];
            }
            a0 = a0 > 0.f ? a0 : expf(a0) - 1.f;
            a1 = a1 > 0.f ? a1 : expf(a1) - 1.f;
        }
        h3b[n * 512 + t] = f2bf(a0);
        h3b[n * 512 + t + 256] = f2bf(a1);
    }
}

extern "C" void kernel_launch(void* const* d_in, const int* in_sizes, int n_in,
                              void* d_out, int out_size, void* d_ws, size_t ws_size,
                              hipStream_t stream) {
    const float* X   = (const float*)d_in[0];
    const int*   ei  = (const int*)d_in[1];
    const float* W1s = (const float*)d_in[2];
    const float* W1d = (const float*)d_in[3];
    const float* a1s = (const float*)d_in[4];
    const float* a1d = (const float*)d_in[5];
    const float* W2s = (const float*)d_in[6];
    const int* src = ei;
    const int* dst = ei + 180000;

    float* out = (float*)d_out;
    float* h2 = out;               // [30000][30]
    float* h4 = out + 900000;      // [30000][3000]

    // scratch inside d_out h4 region (dead before gemm5 overwrites it)
    char* ob = (char*)(out + 900000);
    u16* xs1b = (u16*)ob;                                  // 30080*512
    u16* h1b  = (u16*)(ob + 30801920);                     // 30080*512
    float* g  = (float*)(ob + 30801920 + 30801920);        // 30000*30 fp32

    // ws scratch (must survive gemm5): h3b + W1sT + small vectors
    char* w = (char*)d_ws;
    auto carve = [&](size_t bytes) { char* p = w; w += (bytes + 255) & ~(size_t)255; return p; };
    u16* w1sb  = (u16*)carve((size_t)512 * 3008 * 2);
    u16* w1st  = (u16*)carve((size_t)3072 * 512 * 2);
    u16* w2sb  = (u16*)carve((size_t)128 * 512 * 2);
    u16* h3b   = (u16*)carve((size_t)30080 * 512 * 2);
    float* vd    = (float*)carve(3008 * 4);
    float* vs    = (float*)carve(3008 * 4);
    float* vdp   = (float*)carve(4 * 3008 * 4);
    float* vsp   = (float*)carve(4 * 3008 * 4);
    float* ss    = (float*)carve(30000 * 4);
    float* sd    = (float*)carve(30000 * 4);
    float* alpha = (float*)carve(180000 * 4);
    unsigned* deg = (unsigned*)carve(30000 * 4);
    unsigned* off = (unsigned*)carve(30004 * 4);
    unsigned* cur = (unsigned*)carve(30000 * 4);
    unsigned* csr = (unsigned*)carve(180000 * 4);
    unsigned* bsum = (unsigned*)carve(128 * 4);

    hipMemsetAsync(deg, 0, 30000 * 4, stream);

    // merged prep: vd/vs partials | w1sb | w1st | w2sb | deg
    k_prep<<<2896, 256, 0, stream>>>(W1d, a1d, W1s, a1s, W2s, dst,
                                     vdp, vsp, w1sb, w1st, w2sb, deg);
    k_comb<<<12, 256, 0, stream>>>(vdp, vsp, vd, vs);

    // fused: xs1 = bf16(X) @ W1s^T + sd/ss. Persistent: 768 blocks (3/CU) over 940.
    gemm_xw2<<<768, 256, 0, stream>>>(X, w1sb, xs1b, vd, vs, sd, ss);

    k_scan1<<<118, 256, 0, stream>>>(deg, bsum, 30000);
    k_scanB<<<118, 256, 0, stream>>>(deg, bsum, off, cur, 30000, 118);
    k_fill<<<704, 256, 0, stream>>>(dst, cur, csr);
    k_soft<<<938, 256, 0, stream>>>(src, ss, sd, alpha, csr, off);

    k_agg <<<7520, 256, 0, stream>>>(xs1b, alpha, csr, off, src, h1b, 30000);

    // h2 = h1 @ W2s.T via MFMA (235 tiles)
    gemm_bt<false, true><<<235, 256, 0, stream>>>(h1b, w2sb, h2, 512, 30, 30000, 30, 1, 235);

    // g = agg(alpha, h2);  h3 = elu(g @ W2s)   [agg commutes with linear map]
    k_aggG<<<938, 256, 0, stream>>>(h2, alpha, csr, off, src, g);
    k_h3 <<<3760, 256, 0, stream>>>(g, W2s, h3b);

    // gemm5: persistent 1280 blocks (5/CU at 32KB LDS) over 5640 tiles
    gemm_bt<false, true><<<1280, 256, 0, stream>>>(h3b, w1st, h4, 512, 3000, 30000, 3000, 24, 235);
}